// Round 1
// baseline (498.293 us; speedup 1.0000x reference)
//
#include <hip/hip_runtime.h>

// ExpertRouter: logits = hidden @ W^T + b + routing_bias; softmax; top-2; renorm.
// hidden [4,4096,4096] f32, routing_bias [4,64] f32, W [64,4096] f32, b [64] f32
// out: 32768 f32 weights [B,S,2] ++ 32768 f32 indices [B,S,2]

#define D          4096
#define NE         64
#define TPB        64        // tokens per block
#define KC         32        // K-chunk
#define NCHUNK     (D / KC)  // 128
#define HP         36        // LDS row pitch (dwords), 16B-aligned, stride-4 bank rotation
#define LP         65        // logits LDS pitch

__global__ __launch_bounds__(256)
void router_kernel(const float* __restrict__ hidden,
                   const float* __restrict__ rbias,
                   const float* __restrict__ W,
                   const float* __restrict__ bias,
                   float* __restrict__ out)
{
    __shared__ __align__(16) float Hs[2][TPB][HP];
    __shared__ __align__(16) float Ws[2][NE][HP];
    __shared__ float Ls[NE * LP];
    __shared__ float Bs[NE];

    const int t   = threadIdx.x;
    const int gt0 = blockIdx.x * TPB;
    const int batch = gt0 >> 12;   // 4096 tokens per batch, TPB divides 4096

    if (t < NE) Bs[t] = bias[t] + rbias[batch * NE + t];

    // staging role: thread t loads row (t>>2) of the tile, 16B at k-offset (t&3)*4
    const int row = t >> 2;
    const int kq4 = (t & 3) << 2;
    const float* hrow = hidden + (size_t)(gt0 + row) * D + kq4;
    const float* wrow = W      + (size_t)row * D + kq4;

    // compute role: lane l covers tokens {tq, tq+16, tq+32, tq+48}, experts ebase..ebase+3
    const int l  = t & 63;
    const int w  = t >> 6;
    const int tq = l & 15;
    const int eq = l >> 4;
    const int ebase = w * 16 + eq * 4;

    float acc[4][4] = {};

    // prefetch chunk 0
    float4 ha = *(const float4*)(hrow);
    float4 hb = *(const float4*)(hrow + 16);
    float4 wa = *(const float4*)(wrow);
    float4 wb = *(const float4*)(wrow + 16);
    *(float4*)&Hs[0][row][kq4]      = ha;
    *(float4*)&Hs[0][row][kq4 + 16] = hb;
    *(float4*)&Ws[0][row][kq4]      = wa;
    *(float4*)&Ws[0][row][kq4 + 16] = wb;
    __syncthreads();

    for (int c = 0; c < NCHUNK; ++c) {
        const int buf = c & 1;
        if (c + 1 < NCHUNK) {           // issue next-chunk global loads (in flight over compute)
            const int k0 = (c + 1) * KC;
            ha = *(const float4*)(hrow + k0);
            hb = *(const float4*)(hrow + k0 + 16);
            wa = *(const float4*)(wrow + k0);
            wb = *(const float4*)(wrow + k0 + 16);
        }
        #pragma unroll
        for (int kq = 0; kq < KC / 4; ++kq) {
            float4 hv[4], wv[4];
            #pragma unroll
            for (int i = 0; i < 4; ++i)
                hv[i] = *(const float4*)&Hs[buf][tq + 16 * i][kq * 4];
            #pragma unroll
            for (int j = 0; j < 4; ++j)
                wv[j] = *(const float4*)&Ws[buf][ebase + j][kq * 4];
            #pragma unroll
            for (int i = 0; i < 4; ++i)
                #pragma unroll
                for (int j = 0; j < 4; ++j) {
                    acc[i][j] += hv[i].x * wv[j].x;
                    acc[i][j] += hv[i].y * wv[j].y;
                    acc[i][j] += hv[i].z * wv[j].z;
                    acc[i][j] += hv[i].w * wv[j].w;
                }
        }
        __syncthreads();                 // all waves done reading buf^1
        if (c + 1 < NCHUNK) {
            const int nb = buf ^ 1;
            *(float4*)&Hs[nb][row][kq4]      = ha;
            *(float4*)&Hs[nb][row][kq4 + 16] = hb;
            *(float4*)&Ws[nb][row][kq4]      = wa;
            *(float4*)&Ws[nb][row][kq4 + 16] = wb;
        }
        __syncthreads();                 // next buffer visible
    }

    // scatter logits to LDS: Ls[e][tok]
    #pragma unroll
    for (int i = 0; i < 4; ++i)
        #pragma unroll
        for (int j = 0; j < 4; ++j)
            Ls[(ebase + j) * LP + tq + 16 * i] = acc[i][j];
    __syncthreads();

    // epilogue: one lane per token — online softmax + branchless top-2
    if (t < TPB) {
        const int tok = t;
        float m = -INFINITY, Z = 0.f;
        float v1 = -INFINITY, v2 = -INFINITY;
        int   i1 = 0, i2 = 0;
        for (int e = 0; e < NE; ++e) {
            const float v = Ls[e * LP + tok] + Bs[e];
            const float nm = fmaxf(m, v);
            Z = Z * __expf(m - nm) + __expf(v - nm);
            m = nm;
            const bool g1 = v > v1;
            const bool g2 = v > v2;
            const float nv2 = g1 ? v1 : (g2 ? v : v2);
            const int   ni2 = g1 ? i1 : (g2 ? e : i2);
            v1 = g1 ? v : v1;
            i1 = g1 ? e : i1;
            v2 = nv2;
            i2 = ni2;
        }
        const float p1 = __expf(v1 - m) / Z;
        const float p2 = __expf(v2 - m) / Z;
        const float s  = p1 + p2 + 1e-8f;
        const int gt = gt0 + tok;
        out[gt * 2 + 0] = p1 / s;
        out[gt * 2 + 1] = p2 / s;
        float* outI = out + 4 * 4096 * 2;
        outI[gt * 2 + 0] = (float)i1;
        outI[gt * 2 + 1] = (float)i2;
    }
}

extern "C" void kernel_launch(void* const* d_in, const int* in_sizes, int n_in,
                              void* d_out, int out_size, void* d_ws, size_t ws_size,
                              hipStream_t stream) {
    (void)in_sizes; (void)n_in; (void)d_ws; (void)ws_size; (void)out_size;
    const float* hidden = (const float*)d_in[0];
    const float* rbias  = (const float*)d_in[1];
    const float* W      = (const float*)d_in[2];
    const float* bias   = (const float*)d_in[3];
    float* out = (float*)d_out;

    const int n_tokens = 4 * 4096;
    dim3 grid(n_tokens / TPB);   // 256 blocks
    dim3 block(256);
    hipLaunchKernelGGL(router_kernel, grid, block, 0, stream,
                       hidden, rbias, W, bias, out);
}